// Round 4
// baseline (268.886 us; speedup 1.0000x reference)
//
#include <hip/hip_runtime.h>
#include <math.h>

#define NTHREADS 256               // 4 fully-independent waves per block, no barriers
#define WPB      4                 // rows (waves) per block
#define NELEM    4096              // H*W
#define NREP1    4                 // pass-1 histogram replicas per wave
#define HSTRIDE  260               // words; %4==0 (uint4-aligned), %32==4 (bank spread)
#define CAP      1536              // survivor buffer (words); hot bucket ~1170 (+12 sigma)
#define MAXS     (CAP / 64)        // 24 survivors per lane in registers
#define WAVE_LDS 1536              // words per wave: hist (1040) and cbuf (1536) overlap
#define LDSW     (WPB * WAVE_LDS)  // 6144 words = 24.6 KB/block -> 6 blocks/CU

typedef float v4f __attribute__((ext_vector_type(4)));

// order-preserving float->uint map (ascending), branchless
__device__ __forceinline__ unsigned f2ord(float f) {
    unsigned u = __float_as_uint(f);
    return u ^ ((unsigned)((int)u >> 31) | 0x80000000u);
}
__device__ __forceinline__ float ord2f(unsigned k) {
    return __uint_as_float(k ^ (~(unsigned)((int)k >> 31) | 0x80000000u));
}

// Canonical GCN wave64 inclusive add-scan in the VALU pipe via DPP.
__device__ __forceinline__ unsigned iscan_dpp(unsigned v) {
    v += (unsigned)__builtin_amdgcn_update_dpp(0, (int)v, 0x111, 0xF, 0xF, false);
    v += (unsigned)__builtin_amdgcn_update_dpp(0, (int)v, 0x112, 0xF, 0xF, false);
    v += (unsigned)__builtin_amdgcn_update_dpp(0, (int)v, 0x114, 0xF, 0xF, false);
    v += (unsigned)__builtin_amdgcn_update_dpp(0, (int)v, 0x118, 0xF, 0xF, false);
    v += (unsigned)__builtin_amdgcn_update_dpp(0, (int)v, 0x142, 0xA, 0xF, false);
    v += (unsigned)__builtin_amdgcn_update_dpp(0, (int)v, 0x143, 0xC, 0xF, false);
    return v;
}

struct Pick2 { unsigned a, b; };

// Reduce NR replicas of 256 bins (4 bins/lane), DPP-scan, locate ranks rA,rB.
// Wave-uniform packed result (bucket<<12)|localrank via ballot + v_readlane.
template <int NR>
__device__ __forceinline__ Pick2 wave_pick2(const unsigned* region, int lane,
                                            unsigned rA, unsigned rB) {
    unsigned s0 = 0, s1 = 0, s2 = 0, s3 = 0;
    #pragma unroll
    for (int rep = 0; rep < NR; ++rep) {
        uint4 h = ((const uint4*)(region + rep * HSTRIDE))[lane];
        s0 += h.x; s1 += h.y; s2 += h.z; s3 += h.w;
    }
    unsigned tot = s0 + s1 + s2 + s3;
    unsigned inc = iscan_dpp(tot);
    unsigned ex  = inc - tot;          // exclusive base of this lane's 4 bins
    unsigned base[4] = {ex, ex + s0, ex + s0 + s1, ex + s0 + s1 + s2};
    unsigned cnt[4]  = {s0, s1, s2, s3};
    unsigned resA = 0, resB = 0;
    bool fA = false, fB = false;
    #pragma unroll
    for (int j = 0; j < 4; ++j) {
        if (rA >= base[j] && rA < base[j] + cnt[j]) {
            resA = ((unsigned)(4 * lane + j) << 12) | (rA - base[j]); fA = true;
        }
        if (rB >= base[j] && rB < base[j] + cnt[j]) {
            resB = ((unsigned)(4 * lane + j) << 12) | (rB - base[j]); fB = true;
        }
    }
    unsigned long long mA = __ballot(fA);
    unsigned long long mB = __ballot(fB);
    Pick2 r;
    r.a = (unsigned)__builtin_amdgcn_readlane((int)resA, (int)(__ffsll((long long)mA) - 1));
    r.b = (unsigned)__builtin_amdgcn_readlane((int)resB, (int)(__ffsll((long long)mB) - 1));
    return r;
}

// Re-read the row (L2-hot) and ballot-compact keys whose top byte == bucket
// into cbuf. Returns bucket count (wave-uniform, SGPR).
__device__ __forceinline__ unsigned compact_bucket(const float4* __restrict__ xr,
                                                   int lane, unsigned bucket,
                                                   unsigned* cbuf) {
    unsigned base = 0;
    #pragma unroll 4
    for (int j = 0; j < 16; ++j) {
        float4 v = xr[j * 64 + lane];
        unsigned kk4[4] = {f2ord(v.x), f2ord(v.y), f2ord(v.z), f2ord(v.w)};
        #pragma unroll
        for (int e = 0; e < 4; ++e) {
            unsigned kk = kk4[e];
            bool m = (kk >> 24) == bucket;
            unsigned long long msk = __ballot(m);
            unsigned pos = base + (unsigned)__popcll(msk & ((1ull << lane) - 1ull));
            if (m && pos < CAP) cbuf[pos] = kk;
            base += (unsigned)__popcll(msk);
        }
    }
    return base;
}

__device__ __forceinline__ void load_surv(const unsigned* cbuf, int lane,
                                          unsigned cnt, unsigned S[MAXS]) {
    #pragma unroll
    for (int j = 0; j < MAXS; ++j) {
        unsigned idx = (unsigned)(j * 64 + lane);     // lane-major: 2-way banks (free)
        unsigned w = cbuf[idx];
        S[j] = (idx < cnt) ? w : 0xFFFFFFFFu;          // pad sorts above all candidates
    }
}

// Dual radix bit-descend on the low 24 bits over register survivors.
// Invariant: count(S < pX) <= localRankX. Counts <= 1536 -> pack both in one u32.
__device__ __forceinline__ Pick2 descend24(const unsigned S[MAXS], unsigned bucket,
                                           unsigned rA, unsigned rB) {
    unsigned pA = bucket << 24, pB = bucket << 24;
    #pragma unroll 1
    for (int b = 23; b >= 0; --b) {
        unsigned cA = pA | (1u << b), cB = pB | (1u << b);
        unsigned cntA = 0, cntB = 0;
        #pragma unroll
        for (int j = 0; j < MAXS; ++j) {
            cntA += (S[j] < cA) ? 1u : 0u;
            cntB += (S[j] < cB) ? 1u : 0u;
        }
        unsigned tot = iscan_dpp(cntA | (cntB << 16));
        unsigned t = (unsigned)__builtin_amdgcn_readlane((int)tot, 63);
        if ((t & 0xFFFFu) <= rA) pA = cA;   // wave-uniform scalar branch
        if ((t >> 16)     <= rB) pB = cB;
    }
    Pick2 r; r.a = pA; r.b = pB; return r;
}

__global__ void __launch_bounds__(NTHREADS, 4)
xsrelu_kernel(const float* __restrict__ x, const float* __restrict__ plogit,
              float* __restrict__ out, int C, int nrows) {
    __shared__ __align__(16) unsigned lds[LDSW];   // wave-private regions, no sharing

    const int tid  = threadIdx.x;
    const int wid  = tid >> 6;
    const int lane = tid & 63;
    const int row  = blockIdx.x * WPB + wid;
    if (row >= nrows) return;                      // wave-uniform

    unsigned* wbase = lds + wid * WAVE_LDS;
    const float4* xr = (const float4*)(x + (size_t)row * NELEM);

    float p0 = 1.0f / (1.0f + expf(-plogit[0]));
    float pc = 1.0f / (1.0f + expf(-plogit[row % C]));
    int kLow  = min(max((int)((float)NELEM * (p0 - 0.02f)), 0), NELEM - 1);
    int kHigh = min(max((int)((float)NELEM * (p0 + 0.02f)), 0), NELEM - 1);

    // ---- Phase A: stream row once, 8-bit histogram (keys NOT kept in regs).
    const uint4 z4 = make_uint4(0u, 0u, 0u, 0u);
    #pragma unroll
    for (int r = 0; r < NREP1; ++r)
        ((uint4*)(wbase + r * HSTRIDE))[lane] = z4;
    unsigned* my1 = wbase + (lane & (NREP1 - 1)) * HSTRIDE;
    #pragma unroll
    for (int j = 0; j < 16; ++j) {
        float4 v = xr[j * 64 + lane];
        atomicAdd(&my1[f2ord(v.x) >> 24], 1u);
        atomicAdd(&my1[f2ord(v.y) >> 24], 1u);
        atomicAdd(&my1[f2ord(v.z) >> 24], 1u);
        atomicAdd(&my1[f2ord(v.w) >> 24], 1u);
    }
    Pick2 p1 = wave_pick2<NREP1>(wbase, lane, (unsigned)kLow, (unsigned)kHigh);
    unsigned bA = p1.a >> 12, rA = p1.a & 0xFFFu;
    unsigned bB = p1.b >> 12, rB = p1.b & 0xFFFu;
    bool diverged = (bA != bB);

    // ---- Phase B: compact hot bucket(s) (re-read L2-hot), then VALU-only
    // 24-bit dual bit-descend on register survivors.  (hist region is dead
    // after pick1; cbuf reuses it — same-wave DS ops are in program order.)
    unsigned keyA = 0, keyB = 0;
    bool fb = false;
    if (!diverged) {
        unsigned cnt = compact_bucket(xr, lane, bA, wbase);
        if (cnt <= CAP) {
            unsigned S[MAXS];
            load_surv(wbase, lane, cnt, S);
            Pick2 d = descend24(S, bA, rA, rB);
            keyA = d.a; keyB = d.b;
        } else fb = true;
    } else {
        unsigned cntA = compact_bucket(xr, lane, bA, wbase);
        if (cntA <= CAP) {
            unsigned S[MAXS];
            load_surv(wbase, lane, cntA, S);
            keyA = descend24(S, bA, rA, rA).a;
            unsigned cntB = compact_bucket(xr, lane, bB, wbase);
            if (cntB <= CAP) {
                load_surv(wbase, lane, cntB, S);
                keyB = descend24(S, bB, rB, rB).a;
            } else fb = true;
        } else fb = true;
    }

    // ---- Fallback (bucket > CAP, e.g. near-constant rows): R1-style predicated
    // histogram passes re-reading the row from global. Correct for all inputs.
    if (fb) {
        unsigned* myT = wbase;
        unsigned* myB = wbase + HSTRIDE;
        unsigned known = 0xFF000000u;
        unsigned prefA = bA << 24, prefB = bB << 24;
        unsigned lrA = rA, lrB = rB;
        bool div = diverged;
        #pragma unroll 1
        for (int shift = 16; shift >= 0; shift -= 8) {
            ((uint4*)myT)[lane] = z4;
            if (div) ((uint4*)myB)[lane] = z4;
            #pragma unroll 1
            for (int j = 0; j < 16; ++j) {
                float4 v = xr[j * 64 + lane];
                unsigned kk4[4] = {f2ord(v.x), f2ord(v.y), f2ord(v.z), f2ord(v.w)};
                #pragma unroll
                for (int e = 0; e < 4; ++e) {
                    unsigned kk = kk4[e];
                    unsigned km = kk & known;
                    if (!div) {
                        if (km == prefA)
                            atomicAdd(&myT[(kk >> shift) & 0xFFu], 1u);
                    } else {
                        bool isB = (km == prefB);
                        if ((km == prefA) | isB)
                            atomicAdd((isB ? myB : myT) + ((kk >> shift) & 0xFFu), 1u);
                    }
                }
            }
            if (!div) {
                Pick2 p = wave_pick2<1>(myT, lane, lrA, lrB);
                unsigned cA = p.a >> 12, cB = p.b >> 12;
                prefA |= cA << shift;  lrA = p.a & 0xFFFu;
                prefB |= cB << shift;  lrB = p.b & 0xFFFu;
                div = (cA != cB);
            } else {
                unsigned pa = wave_pick2<1>(myT, lane, lrA, lrA).a;
                unsigned pb = wave_pick2<1>(myB, lane, lrB, lrB).a;
                prefA |= (pa >> 12) << shift;  lrA = pa & 0xFFFu;
                prefB |= (pb >> 12) << shift;  lrB = pb & 0xFFFu;
            }
            known |= 0xFFu << shift;
        }
        keyA = prefA; keyB = prefB;
    }

    float xlow  = ord2f(keyA);
    float xhigh = ord2f(keyB);
    float thr = xlow + (xhigh - xlow) * pc;

    // ---- Epilogue: re-read raw row (L2/L3-hot), relu, nontemporal stream out.
    v4f* outr = (v4f*)(out + (size_t)row * NELEM);
    #pragma unroll
    for (int j = 0; j < 16; ++j) {
        float4 v = xr[j * 64 + lane];
        v4f o;
        o.x = fmaxf(v.x - thr, 0.0f);
        o.y = fmaxf(v.y - thr, 0.0f);
        o.z = fmaxf(v.z - thr, 0.0f);
        o.w = fmaxf(v.w - thr, 0.0f);
        __builtin_nontemporal_store(o, outr + j * 64 + lane);
    }
}

extern "C" void kernel_launch(void* const* d_in, const int* in_sizes, int n_in,
                              void* d_out, int out_size, void* d_ws, size_t ws_size,
                              hipStream_t stream) {
    const float* x      = (const float*)d_in[0];
    const float* plogit = (const float*)d_in[1];
    float* out          = (float*)d_out;
    int C    = in_sizes[1];              // 256
    int rows = in_sizes[0] / NELEM;      // 8192
    int grid = (rows + WPB - 1) / WPB;   // 2048 blocks
    xsrelu_kernel<<<grid, NTHREADS, 0, stream>>>(x, plogit, out, C, rows);
}

// Round 5
// 242.235 us; speedup vs baseline: 1.1100x; 1.1100x over previous
//
#include <hip/hip_runtime.h>
#include <math.h>

#define NTHREADS 256               // 4 fully-independent waves per block, no barriers
#define WPB      4                 // waves per block
#define WPW      2                 // rows per wave (software pipeline depth 2)
#define NELEM    4096              // H*W
#define EPL      64                // keys per lane
#define NREP1    4                 // pass-1 histogram replicas per wave
#define HSTRIDE  260               // words; %4==0 (uint4-aligned), %32==4 (bank spread)
#define WAVE_LDS (NREP1 * HSTRIDE) // 1040 words per wave
#define LDSW     (WPB * WAVE_LDS)  // 4160 words = 16.6 KB/block

typedef float v4f __attribute__((ext_vector_type(4)));

// order-preserving float->uint map (ascending), branchless
__device__ __forceinline__ unsigned f2ord(float f) {
    unsigned u = __float_as_uint(f);
    return u ^ ((unsigned)((int)u >> 31) | 0x80000000u);
}
__device__ __forceinline__ float ord2f(unsigned k) {
    return __uint_as_float(k ^ (~(unsigned)((int)k >> 31) | 0x80000000u));
}

// Canonical GCN wave64 inclusive add-scan in the VALU pipe via DPP.
__device__ __forceinline__ unsigned iscan_dpp(unsigned v) {
    v += (unsigned)__builtin_amdgcn_update_dpp(0, (int)v, 0x111, 0xF, 0xF, false);
    v += (unsigned)__builtin_amdgcn_update_dpp(0, (int)v, 0x112, 0xF, 0xF, false);
    v += (unsigned)__builtin_amdgcn_update_dpp(0, (int)v, 0x114, 0xF, 0xF, false);
    v += (unsigned)__builtin_amdgcn_update_dpp(0, (int)v, 0x118, 0xF, 0xF, false);
    v += (unsigned)__builtin_amdgcn_update_dpp(0, (int)v, 0x142, 0xA, 0xF, false);
    v += (unsigned)__builtin_amdgcn_update_dpp(0, (int)v, 0x143, 0xC, 0xF, false);
    return v;
}

struct Pick2 { unsigned a, b; };

// Reduce NR replicas of 256 bins (4 bins/lane), DPP-scan, locate ranks rA,rB.
template <int NR>
__device__ __forceinline__ Pick2 wave_pick2(const unsigned* region, int lane,
                                            unsigned rA, unsigned rB) {
    unsigned s0 = 0, s1 = 0, s2 = 0, s3 = 0;
    #pragma unroll
    for (int rep = 0; rep < NR; ++rep) {
        uint4 h = ((const uint4*)(region + rep * HSTRIDE))[lane];
        s0 += h.x; s1 += h.y; s2 += h.z; s3 += h.w;
    }
    unsigned tot = s0 + s1 + s2 + s3;
    unsigned inc = iscan_dpp(tot);
    unsigned ex  = inc - tot;
    unsigned base[4] = {ex, ex + s0, ex + s0 + s1, ex + s0 + s1 + s2};
    unsigned cnt[4]  = {s0, s1, s2, s3};
    unsigned resA = 0, resB = 0;
    bool fA = false, fB = false;
    #pragma unroll
    for (int j = 0; j < 4; ++j) {
        if (rA >= base[j] && rA < base[j] + cnt[j]) {
            resA = ((unsigned)(4 * lane + j) << 12) | (rA - base[j]); fA = true;
        }
        if (rB >= base[j] && rB < base[j] + cnt[j]) {
            resB = ((unsigned)(4 * lane + j) << 12) | (rB - base[j]); fB = true;
        }
    }
    unsigned long long mA = __ballot(fA);
    unsigned long long mB = __ballot(fB);
    Pick2 r;
    r.a = (unsigned)__builtin_amdgcn_readlane((int)resA, (int)(__ffsll((long long)mA) - 1));
    r.b = (unsigned)__builtin_amdgcn_readlane((int)resB, (int)(__ffsll((long long)mB) - 1));
    return r;
}

struct Keys2 { unsigned a, b; };

// R1's proven 4-pass radix selection over register keys (wave-private LDS hist).
__device__ __forceinline__ Keys2 select2(unsigned* wbase, const unsigned k[EPL],
                                         int lane, unsigned kLow, unsigned kHigh) {
    const uint4 z4 = make_uint4(0u, 0u, 0u, 0u);
    unsigned* my1 = wbase + (lane & (NREP1 - 1)) * HSTRIDE;
    #pragma unroll
    for (int r = 0; r < NREP1; ++r)
        ((uint4*)(wbase + r * HSTRIDE))[lane] = z4;
    #pragma unroll
    for (int j = 0; j < EPL; ++j)
        atomicAdd(&my1[k[j] >> 24], 1u);
    Pick2 p1 = wave_pick2<NREP1>(wbase, lane, kLow, kHigh);
    unsigned bA = p1.a >> 12, bB = p1.b >> 12;
    unsigned prefA = bA << 24, rA = p1.a & 0xFFFu;
    unsigned prefB = bB << 24, rB = p1.b & 0xFFFu;
    unsigned known = 0xFF000000u;
    bool diverged = (bA != bB);

    unsigned* myT = wbase;
    unsigned* myB = wbase + HSTRIDE;
    #pragma unroll 1
    for (int shift = 16; shift >= 0; shift -= 8) {
        if (!diverged) {
            ((uint4*)myT)[lane] = z4;
            #pragma unroll
            for (int j = 0; j < EPL; ++j) {
                unsigned kk = k[j];
                if ((kk & known) == prefA)
                    atomicAdd(&myT[(kk >> shift) & 0xFFu], 1u);
            }
            Pick2 p = wave_pick2<1>(myT, lane, rA, rB);
            unsigned cA = p.a >> 12, cB = p.b >> 12;
            prefA |= cA << shift;  rA = p.a & 0xFFFu;
            prefB |= cB << shift;  rB = p.b & 0xFFFu;
            diverged = (cA != cB);
        } else {
            ((uint4*)myT)[lane] = z4;
            ((uint4*)myB)[lane] = z4;
            #pragma unroll
            for (int j = 0; j < EPL; ++j) {
                unsigned kk = k[j];
                unsigned km = kk & known;
                bool isB = (km == prefB);
                if ((km == prefA) | isB)
                    atomicAdd((isB ? myB : myT) + ((kk >> shift) & 0xFFu), 1u);
            }
            unsigned pa = wave_pick2<1>(myT, lane, rA, rA).a;
            unsigned pb = wave_pick2<1>(myB, lane, rB, rB).a;
            prefA |= (pa >> 12) << shift;  rA = pa & 0xFFFu;
            prefB |= (pb >> 12) << shift;  rB = pb & 0xFFFu;
        }
        known |= 0xFFu << shift;
    }
    Keys2 r; r.a = prefA; r.b = prefB; return r;
}

__device__ __forceinline__ void epilogue(const unsigned k[EPL], float thr,
                                         float* __restrict__ orow, int lane) {
    v4f* outr = (v4f*)orow;
    #pragma unroll
    for (int j = 0; j < EPL / 4; ++j) {
        v4f o;
        o.x = fmaxf(ord2f(k[4 * j + 0]) - thr, 0.0f);
        o.y = fmaxf(ord2f(k[4 * j + 1]) - thr, 0.0f);
        o.z = fmaxf(ord2f(k[4 * j + 2]) - thr, 0.0f);
        o.w = fmaxf(ord2f(k[4 * j + 3]) - thr, 0.0f);
        __builtin_nontemporal_store(o, outr + j * 64 + lane);
    }
}

__global__ void __launch_bounds__(NTHREADS, 3)
xsrelu_kernel(const float* __restrict__ x, const float* __restrict__ plogit,
              float* __restrict__ out, int C, int nrows) {
    __shared__ __align__(16) unsigned hist[LDSW];   // wave-private regions, no sharing

    const int tid  = threadIdx.x;
    const int wid  = tid >> 6;
    const int lane = tid & 63;
    const int wave = blockIdx.x * WPB + wid;
    const int row0 = wave * WPW;
    if (row0 >= nrows) return;                      // wave-uniform
    const bool have1 = (row0 + 1) < nrows;

    unsigned* wbase = hist + wid * WAVE_LDS;
    const float4* xr0 = (const float4*)(x + (size_t)row0 * NELEM);
    const float4* xr1 = (const float4*)(x + (size_t)(row0 + 1) * NELEM);

    // ---- Load row0 -> keys in regs.
    unsigned k[EPL];
    #pragma unroll
    for (int j = 0; j < EPL / 4; ++j) {
        float4 v = xr0[j * 64 + lane];
        k[4 * j + 0] = f2ord(v.x);
        k[4 * j + 1] = f2ord(v.y);
        k[4 * j + 2] = f2ord(v.z);
        k[4 * j + 3] = f2ord(v.w);
    }
    // ---- Issue row1 prefetch NOW; it flies during row0's selection.
    float4 nx[EPL / 4];
    if (have1) {
        #pragma unroll
        for (int j = 0; j < EPL / 4; ++j)
            nx[j] = xr1[j * 64 + lane];
    }
    // Fence: nothing (esp. the prefetch loads) may be reordered across this
    // point — keeps the 16 KB of row1 in flight under row0's selection chain.
    __builtin_amdgcn_sched_barrier(0);

    // Row-uniform scalars.
    float p0 = 1.0f / (1.0f + expf(-plogit[0]));
    unsigned kLow  = (unsigned)min(max((int)((float)NELEM * (p0 - 0.02f)), 0), NELEM - 1);
    unsigned kHigh = (unsigned)min(max((int)((float)NELEM * (p0 + 0.02f)), 0), NELEM - 1);
    float pc0 = 1.0f / (1.0f + expf(-plogit[row0 % C]));
    float pc1 = 1.0f / (1.0f + expf(-plogit[(row0 + 1) % C]));

    // ---- Row 0: select + epilogue (stores are fire-and-forget).
    Keys2 s0 = select2(wbase, k, lane, kLow, kHigh);
    float xl0 = ord2f(s0.a), xh0 = ord2f(s0.b);
    epilogue(k, xl0 + (xh0 - xl0) * pc0, out + (size_t)row0 * NELEM, lane);

    if (!have1) return;

    // ---- Convert prefetched row1 (waitcnt lands here, ~whole selection later).
    #pragma unroll
    for (int j = 0; j < EPL / 4; ++j) {
        k[4 * j + 0] = f2ord(nx[j].x);
        k[4 * j + 1] = f2ord(nx[j].y);
        k[4 * j + 2] = f2ord(nx[j].z);
        k[4 * j + 3] = f2ord(nx[j].w);
    }

    // ---- Row 1: select + epilogue. Same LDS region; same-wave DS ops are
    // program-ordered, so no barrier needed between row0 picks and row1 zeroing.
    Keys2 s1 = select2(wbase, k, lane, kLow, kHigh);
    float xl1 = ord2f(s1.a), xh1 = ord2f(s1.b);
    epilogue(k, xl1 + (xh1 - xl1) * pc1, out + (size_t)(row0 + 1) * NELEM, lane);
}

extern "C" void kernel_launch(void* const* d_in, const int* in_sizes, int n_in,
                              void* d_out, int out_size, void* d_ws, size_t ws_size,
                              hipStream_t stream) {
    const float* x      = (const float*)d_in[0];
    const float* plogit = (const float*)d_in[1];
    float* out          = (float*)d_out;
    int C    = in_sizes[1];                       // 256
    int rows = in_sizes[0] / NELEM;               // 8192
    int grid = (rows + WPB * WPW - 1) / (WPB * WPW);   // 1024 blocks
    xsrelu_kernel<<<grid, NTHREADS, 0, stream>>>(x, plogit, out, C, rows);
}